// Round 7
// baseline (835.729 us; speedup 1.0000x reference)
//
#include <hip/hip_runtime.h>
#include <hip/hip_bf16.h>

#define NBAND 7
#define BBATCH 16
#define TSEQ 512
#define DMODEL 128
#define MBAND (BBATCH * TSEQ)               // 8192 rows per band
#define BANDE ((size_t)MBAND * DMODEL)      // 1,048,576 elements per band

typedef __attribute__((ext_vector_type(8))) short short8;
typedef __attribute__((ext_vector_type(4))) float f32x4;

__device__ __forceinline__ unsigned short f2bf(float x) {
  unsigned u = __float_as_uint(x);
  unsigned r = u + 0x7FFF + ((u >> 16) & 1);   // RNE
  return (unsigned short)(r >> 16);
}
__device__ __forceinline__ unsigned pack2(float a, float b) {
  return (unsigned)f2bf(a) | ((unsigned)f2bf(b) << 16);
}

// ===========================================================================
// Row-block GEMM: grid (M/64, y, Z). Block stages full 64x128 A-tile once
// per K-block (A-frags in regs), loops NC 64-col chunks restaging only B.
// C_chunk = epi( A@W_chunk [+ A2@W2_chunk] + bias_chunk )
// ===========================================================================
struct RB {
  const float *A, *A2;
  size_t Aoffz[8], A2offz[8], Woffz[8], boffz[8], roffz[8], eoffz[8], Ooffz[8];
  const float* Wc[8];
  const float* W2c[8];
  const float* biasc[8];
  const float* Rc[8];
  const float* Ec[8];
  float* Oc[8];
  int K, WS, OS, op;   // op: 0 store 1 gelu 2 sigmoid 3 resid+ 4 resid+sig(v)*extra 5 resid+extra*v
};

template <int NC>
__global__ __launch_bounds__(256) void gemm_rb(RB p) {
  __shared__ __align__(16) unsigned short As[64][136];
  __shared__ __align__(16) unsigned short Bs[64][136];
  const int m0 = blockIdx.x * 64;
  const int z  = blockIdx.z;
  const int cbase = blockIdx.y * NC;
  const int tid = threadIdx.x;
  const int lane = tid & 63, wv = tid >> 6;
  const int wr = wv >> 1, wc = wv & 1;
  const int lr = lane & 15, lg = lane >> 4;

  f32x4 acc[NC][2][2] = {};
  const int nparts = p.A2 ? 2 : 1;

  for (int part = 0; part < nparts; ++part) {
    const float* Ab = part ? p.A2 + p.A2offz[z] : p.A + p.Aoffz[z];
    for (int kb = 0; kb < p.K; kb += 128) {
      __syncthreads();                       // prior readers of As/Bs done
      #pragma unroll
      for (int it = 0; it < 8; ++it) {       // stage A 64x128 (packed writes)
        int idx = tid + it * 256;
        int row = idx >> 5, kq = (idx & 31) << 2;
        const float4 a = *(const float4*)&Ab[(size_t)(m0 + row) * p.K + kb + kq];
        *(unsigned*)&As[row][kq]     = pack2(a.x, a.y);
        *(unsigned*)&As[row][kq + 2] = pack2(a.z, a.w);
      }
      __syncthreads();
      short8 af[2][4];
      #pragma unroll
      for (int i = 0; i < 2; ++i)
        #pragma unroll
        for (int ks = 0; ks < 4; ++ks)
          af[i][ks] = *(const short8*)&As[wr * 32 + i * 16 + lr][ks * 32 + lg * 8];

      #pragma unroll
      for (int c = 0; c < NC; ++c) {
        const float* Wp = (part ? p.W2c[cbase + c] : p.Wc[cbase + c]) + p.Woffz[z];
        if (c) __syncthreads();              // chunk c-1 B-frag reads done
        #pragma unroll
        for (int it = 0; it < 4; ++it) {     // stage B chunk 128k x 64n, transposed+packed
          int idx = tid + it * 256;
          int kp = idx >> 4, nq = (idx & 15) << 2;
          const float4 w0 = *(const float4*)&Wp[(size_t)(kb + 2 * kp) * p.WS + nq];
          const float4 w1 = *(const float4*)&Wp[(size_t)(kb + 2 * kp + 1) * p.WS + nq];
          *(unsigned*)&Bs[nq + 0][2 * kp] = pack2(w0.x, w1.x);
          *(unsigned*)&Bs[nq + 1][2 * kp] = pack2(w0.y, w1.y);
          *(unsigned*)&Bs[nq + 2][2 * kp] = pack2(w0.z, w1.z);
          *(unsigned*)&Bs[nq + 3][2 * kp] = pack2(w0.w, w1.w);
        }
        __syncthreads();
        #pragma unroll
        for (int ks = 0; ks < 4; ++ks) {
          short8 b0 = *(const short8*)&Bs[wc * 32 + lr][ks * 32 + lg * 8];
          short8 b1 = *(const short8*)&Bs[wc * 32 + 16 + lr][ks * 32 + lg * 8];
          acc[c][0][0] = __builtin_amdgcn_mfma_f32_16x16x32_bf16(af[0][ks], b0, acc[c][0][0], 0, 0, 0);
          acc[c][0][1] = __builtin_amdgcn_mfma_f32_16x16x32_bf16(af[0][ks], b1, acc[c][0][1], 0, 0, 0);
          acc[c][1][0] = __builtin_amdgcn_mfma_f32_16x16x32_bf16(af[1][ks], b0, acc[c][1][0], 0, 0, 0);
          acc[c][1][1] = __builtin_amdgcn_mfma_f32_16x16x32_bf16(af[1][ks], b1, acc[c][1][1], 0, 0, 0);
        }
      }
    }
  }

  #pragma unroll
  for (int c = 0; c < NC; ++c) {
    int cc = cbase + c;
    const float* bias  = p.biasc[cc] ? p.biasc[cc] + p.boffz[z] : nullptr;
    const float* resid = p.Rc[cc]    ? p.Rc[cc]    + p.roffz[z] : nullptr;
    const float* extra = p.Ec[cc]    ? p.Ec[cc]    + p.eoffz[z] : nullptr;
    float* O = p.Oc[cc] + p.Ooffz[z];
    #pragma unroll
    for (int i = 0; i < 2; ++i)
      #pragma unroll
      for (int j = 0; j < 2; ++j)
        #pragma unroll
        for (int r = 0; r < 4; ++r) {
          int m = m0 + wr * 32 + i * 16 + lg * 4 + r;
          int ncol = wc * 32 + j * 16 + lr;
          float v = acc[c][i][j][r];
          if (bias) v += bias[ncol];
          size_t idx = (size_t)m * p.OS + ncol;
          switch (p.op) {
            case 0: O[idx] = v; break;
            case 1: O[idx] = 0.5f * v * (1.f + erff(v * 0.70710678118654752f)); break;
            case 2: O[idx] = 1.f / (1.f + __expf(-v)); break;
            case 3: O[idx] = resid[idx] + v; break;
            case 4: {
              float gate = 1.f / (1.f + __expf(-v));
              O[idx] = resid[idx] + gate * extra[idx];
            } break;
            case 5: {
              float gm = extra ? extra[idx] : 1.f;
              O[idx] = resid[idx] + gm * v;
            } break;
          }
        }
  }
}

// ===========================================================================
// Old-style 64x64 helper (kept for the 6-part bridge only)
// ===========================================================================
__device__ __forceinline__ void mfma_part(const float* __restrict__ A,
                                          const float* __restrict__ W,
                                          int K, int N, int m0, int n0, int tid,
                                          unsigned short (*As)[40],
                                          unsigned short (*Bs)[40],
                                          f32x4 acc[2][2]) {
  const int lane = tid & 63;
  const int wv = tid >> 6;
  const int wr = wv >> 1, wc = wv & 1;
  const int lr = lane & 15, k8 = lane >> 4;

  for (int k0 = 0; k0 < K; k0 += 32) {
    #pragma unroll
    for (int it = 0; it < 2; ++it) {
      int t = tid + it * 256;
      int m = t >> 3, kq = (t & 7) << 2;
      const float4 v = *(const float4*)&A[(size_t)(m0 + m) * K + k0 + kq];
      *(unsigned*)&As[m][kq]     = pack2(v.x, v.y);
      *(unsigned*)&As[m][kq + 2] = pack2(v.z, v.w);
    }
    #pragma unroll
    for (int it = 0; it < 2; ++it) {
      int t = tid + it * 256;
      int k = t >> 4, nq = (t & 15) << 2;
      const float4 v = *(const float4*)&W[(size_t)(k0 + k) * N + n0 + nq];
      Bs[nq + 0][k] = f2bf(v.x); Bs[nq + 1][k] = f2bf(v.y);
      Bs[nq + 2][k] = f2bf(v.z); Bs[nq + 3][k] = f2bf(v.w);
    }
    __syncthreads();
    short8 a0 = *(const short8*)&As[wr * 32 + lr][k8 * 8];
    short8 a1 = *(const short8*)&As[wr * 32 + 16 + lr][k8 * 8];
    short8 b0 = *(const short8*)&Bs[wc * 32 + lr][k8 * 8];
    short8 b1 = *(const short8*)&Bs[wc * 32 + 16 + lr][k8 * 8];
    acc[0][0] = __builtin_amdgcn_mfma_f32_16x16x32_bf16(a0, b0, acc[0][0], 0, 0, 0);
    acc[0][1] = __builtin_amdgcn_mfma_f32_16x16x32_bf16(a0, b1, acc[0][1], 0, 0, 0);
    acc[1][0] = __builtin_amdgcn_mfma_f32_16x16x32_bf16(a1, b0, acc[1][0], 0, 0, 0);
    acc[1][1] = __builtin_amdgcn_mfma_f32_16x16x32_bf16(a1, b1, acc[1][1], 0, 0, 0);
    __syncthreads();
  }
}

__global__ __launch_bounds__(256) void bridge_kernel(const float* __restrict__ yb,
                                                     const float* __restrict__ br_w,
                                                     const float* __restrict__ bbias,
                                                     float* __restrict__ O) {
  __shared__ __align__(16) unsigned short As[64][40];
  __shared__ __align__(16) unsigned short Bs[64][40];
  const int m0 = blockIdx.x * 64, n0 = blockIdx.y * 64;
  const int tid = threadIdx.x;
  f32x4 acc[2][2] = {};
  const int bl[6] = {0, 1, 2, 4, 5, 6};
  for (int j = 0; j < 6; ++j)
    mfma_part(yb + (size_t)bl[j] * BANDE, br_w + j * 16384, 128, 128, m0, n0, tid, As, Bs, acc);

  const int lane = tid & 63;
  const int wv = tid >> 6;
  const int wr = wv >> 1, wc = wv & 1;
  const int lr = lane & 15, lg = lane >> 4;
  #pragma unroll
  for (int i = 0; i < 2; ++i)
    #pragma unroll
    for (int j = 0; j < 2; ++j)
      #pragma unroll
      for (int r = 0; r < 4; ++r) {
        int m = m0 + wr * 32 + i * 16 + lg * 4 + r;
        int n = n0 + wc * 32 + j * 16 + lr;
        O[(size_t)m * 128 + n] = acc[i][j][r] * (1.f / 6.f) + bbias[n];
      }
}

// ===========================================================================
// MFMA flash attention, causal. H=2, HD=64, T=512, multi-band.
// Bank-conflict-free staging: Q/K packed u32 writes; V transposed via
// dword-packed key-pair writes (<=2-way).
// ===========================================================================
__global__ __launch_bounds__(256) void attn_kernel(const float* __restrict__ q,
                                                   const float* __restrict__ k,
                                                   const float* __restrict__ v,
                                                   float* __restrict__ o) {
  const int band = blockIdx.x >> 8;
  const int rest = blockIdx.x & 255;
  const int qt = rest & 7;
  const int bh = rest >> 3;
  const int h  = bh & 1;
  const int b  = bh >> 1;
  const size_t rowbase = ((size_t)band * BBATCH + b) * TSEQ;

  const int tid  = threadIdx.x;
  const int w    = tid >> 6;
  const int lane = tid & 63;
  const int lr   = lane & 15;
  const int lg   = lane >> 4;

  __shared__ __align__(16) unsigned short Qs[64][72];
  __shared__ __align__(16) unsigned short Ks[64][72];          // [key][dim]
  __shared__ __align__(16) unsigned short Vs[64][72];          // [dim][key]
  __shared__ __align__(16) unsigned short Ps[4][16][72];       // per-wave P

  #pragma unroll
  for (int it = 0; it < 4; ++it) {
    int idx = tid + it * 256;
    int r = idx >> 4, dq = (idx & 15) << 2;
    const float4 val = *(const float4*)&q[(rowbase + qt * 64 + r) * DMODEL + h * 64 + dq];
    *(unsigned*)&Qs[r][dq]     = pack2(val.x * 0.125f, val.y * 0.125f);
    *(unsigned*)&Qs[r][dq + 2] = pack2(val.z * 0.125f, val.w * 0.125f);
  }

  f32x4 oacc[4] = {};
  float m[4], l[4];
  #pragma unroll
  for (int r = 0; r < 4; ++r) { m[r] = -1e30f; l[r] = 0.f; }

  for (int kt = 0; kt <= qt; ++kt) {
    __syncthreads();
    #pragma unroll
    for (int it = 0; it < 4; ++it) {       // K: [key][dim], packed row writes
      int idx = tid + it * 256;
      int r = idx >> 4, dq = (idx & 15) << 2;
      const float4 kv = *(const float4*)&k[(rowbase + kt * 64 + r) * DMODEL + h * 64 + dq];
      *(unsigned*)&Ks[r][dq]     = pack2(kv.x, kv.y);
      *(unsigned*)&Ks[r][dq + 2] = pack2(kv.z, kv.w);
    }
    #pragma unroll
    for (int it = 0; it < 2; ++it) {       // V: [dim][key], key-pair packed
      int idx = tid + it * 256;            // 0..511
      int kp = idx >> 4;                   // key pair 0..31
      int d0 = (idx & 15) << 2;
      size_t g0 = (rowbase + kt * 64 + 2 * kp) * DMODEL + h * 64 + d0;
      const float4 va = *(const float4*)&v[g0];
      const float4 vb = *(const float4*)&v[g0 + DMODEL];
      *(unsigned*)&Vs[d0 + 0][2 * kp] = pack2(va.x, vb.x);
      *(unsigned*)&Vs[d0 + 1][2 * kp] = pack2(va.y, vb.y);
      *(unsigned*)&Vs[d0 + 2][2 * kp] = pack2(va.z, vb.z);
      *(unsigned*)&Vs[d0 + 3][2 * kp] = pack2(va.w, vb.w);
    }
    __syncthreads();

    // ---- QK^T
    f32x4 s[4] = {};
    #pragma unroll
    for (int c = 0; c < 2; ++c) {
      short8 a = *(const short8*)&Qs[w * 16 + lr][c * 32 + lg * 8];
      #pragma unroll
      for (int j = 0; j < 4; ++j) {
        short8 bb = *(const short8*)&Ks[j * 16 + lr][c * 32 + lg * 8];
        s[j] = __builtin_amdgcn_mfma_f32_16x16x32_bf16(a, bb, s[j], 0, 0, 0);
      }
    }

    if (kt == qt) {
      #pragma unroll
      for (int j = 0; j < 4; ++j)
        #pragma unroll
        for (int r = 0; r < 4; ++r) {
          int row = w * 16 + lg * 4 + r;
          int col = j * 16 + lr;
          if (col > row) s[j][r] = -1e30f;
        }
    }

    // ---- online softmax
    float mx[4], al[4];
    #pragma unroll
    for (int r = 0; r < 4; ++r)
      mx[r] = fmaxf(fmaxf(s[0][r], s[1][r]), fmaxf(s[2][r], s[3][r]));
    #pragma unroll
    for (int off = 1; off <= 8; off <<= 1)
      #pragma unroll
      for (int r = 0; r < 4; ++r)
        mx[r] = fmaxf(mx[r], __shfl_xor(mx[r], off));
    #pragma unroll
    for (int r = 0; r < 4; ++r) {
      float mn = fmaxf(m[r], mx[r]);
      al[r] = __expf(m[r] - mn);
      m[r] = mn;
    }
    float rs[4] = {0.f, 0.f, 0.f, 0.f};
    #pragma unroll
    for (int j = 0; j < 4; ++j)
      #pragma unroll
      for (int r = 0; r < 4; ++r) {
        float pe = __expf(s[j][r] - m[r]);
        s[j][r] = pe;
        rs[r] += pe;
      }
    #pragma unroll
    for (int off = 1; off <= 8; off <<= 1)
      #pragma unroll
      for (int r = 0; r < 4; ++r)
        rs[r] += __shfl_xor(rs[r], off);
    #pragma unroll
    for (int r = 0; r < 4; ++r) l[r] = l[r] * al[r] + rs[r];

    #pragma unroll
    for (int j = 0; j < 4; ++j)
      #pragma unroll
      for (int r = 0; r < 4; ++r)
        oacc[j][r] *= al[r];

    // ---- P transpose via per-wave LDS
    #pragma unroll
    for (int j = 0; j < 4; ++j)
      #pragma unroll
      for (int r = 0; r < 4; ++r)
        Ps[w][lg * 4 + r][j * 16 + lr] = f2bf(s[j][r]);

    // ---- PV
    #pragma unroll
    for (int c = 0; c < 2; ++c) {
      short8 a = *(const short8*)&Ps[w][lr][c * 32 + lg * 8];
      #pragma unroll
      for (int j = 0; j < 4; ++j) {
        short8 bb = *(const short8*)&Vs[j * 16 + lr][c * 32 + lg * 8];
        oacc[j] = __builtin_amdgcn_mfma_f32_16x16x32_bf16(a, bb, oacc[j], 0, 0, 0);
      }
    }
  }

  float inv[4];
  #pragma unroll
  for (int r = 0; r < 4; ++r) inv[r] = 1.f / l[r];
  #pragma unroll
  for (int j = 0; j < 4; ++j)
    #pragma unroll
    for (int r = 0; r < 4; ++r) {
      size_t row = rowbase + qt * 64 + w * 16 + lg * 4 + r;
      o[row * DMODEL + h * 64 + j * 16 + lr] = oacc[j][r] * inv[r];
    }
}

// ---------------------------------------------------------------------------
struct LNA {
  const float* x;
  float* xn;
  const float* ls[7];
  const float* lb[7];
};

__global__ __launch_bounds__(256) void ln_kernel(LNA p) {
  const int tid = threadIdx.x;
  const int rr = tid >> 6, lane = tid & 63;
  const size_t row = (size_t)blockIdx.x * 4 + rr;
  const float* xp = p.x + row * DMODEL;
  float a = xp[lane], b = xp[lane + 64];
  float s = a + b;
  #pragma unroll
  for (int off = 32; off; off >>= 1) s += __shfl_xor(s, off);
  float mean = s * (1.f / 128.f);
  float da = a - mean, db = b - mean;
  float vs = da * da + db * db;
  #pragma unroll
  for (int off = 32; off; off >>= 1) vs += __shfl_xor(vs, off);
  float rstd = rsqrtf(vs * (1.f / 128.f) + 1e-5f);
  int band = (int)(row >> 13);
  const float* ls = p.ls[band];
  const float* lb = p.lb[band];
  float* op = p.xn + row * DMODEL;
  op[lane]      = da * rstd * ls[lane]      + lb[lane];
  op[lane + 64] = db * rstd * ls[lane + 64] + lb[lane + 64];
}

__global__ void bias6_kernel(const float* __restrict__ br_b, float* __restrict__ out) {
  int d = threadIdx.x;
  float s = 0.f;
  #pragma unroll
  for (int j = 0; j < 6; ++j) s += br_b[j * 128 + d];
  out[d] = s * (1.f / 6.f);
}

// ---------------------------------------------------------------------------
extern "C" void kernel_launch(void* const* d_in, const int* in_sizes, int n_in,
                              void* d_out, int out_size, void* d_ws, size_t ws_size,
                              hipStream_t stream) {
  bool dict = (in_sizes[2] != 896);
  const float* bands = (const float*)d_in[0];
  const float* Wq = (const float*)d_in[1];
  const float *Wk, *Wv, *Wo, *bq, *bk, *bv, *bo;
  if (dict) {
    Wk = (const float*)d_in[2]; Wv = (const float*)d_in[3]; Wo = (const float*)d_in[4];
    bq = (const float*)d_in[5]; bk = (const float*)d_in[6];
    bv = (const float*)d_in[7]; bo = (const float*)d_in[8];
  } else {
    bq = (const float*)d_in[2]; Wk = (const float*)d_in[3]; bk = (const float*)d_in[4];
    Wv = (const float*)d_in[5]; bv = (const float*)d_in[6];
    Wo = (const float*)d_in[7]; bo = (const float*)d_in[8];
  }
  const float* g_ls = (const float*)d_in[9];
  const float* g_lb = (const float*)d_in[10];
  const float* g_w1 = (const float*)d_in[11];
  const float* g_b1 = (const float*)d_in[12];
  const float* g_w2 = (const float*)d_in[13];
  const float* g_b2 = (const float*)d_in[14];
  const float* g_wg = (const float*)d_in[15];
  const float* g_bg = (const float*)d_in[16];
  const float* h_ls = (const float*)d_in[17];
  const float* h_lb = (const float*)d_in[18];
  const float* h_w1 = (const float*)d_in[19];
  const float* h_b1 = (const float*)d_in[20];
  const float* h_w2 = (const float*)d_in[21];
  const float* h_b2 = (const float*)d_in[22];
  const float* r_ls = (const float*)d_in[23];
  const float* r_lb = (const float*)d_in[24];
  const float* r_w1 = (const float*)d_in[25];
  const float* r_b1 = (const float*)d_in[26];
  const float* r_w2 = (const float*)d_in[27];
  const float* r_b2 = (const float*)d_in[28];
  const float* wp_w = (const float*)d_in[29];
  const float* wp_b = (const float*)d_in[30];
  const float* wg_w = (const float*)d_in[31];
  const float* wg_b = (const float*)d_in[32];
  const float* br_w = (const float*)d_in[33];
  const float* br_b = (const float*)d_in[34];
  const float* bg_w = (const float*)d_in[35];
  const float* bg_b = (const float*)d_in[36];
  float* out = (float*)d_out;

  const float* lsP[7] = {g_ls, g_ls + 128, g_ls + 256, h_ls, h_ls + 128, r_ls, r_ls + 128};
  const float* lbP[7] = {g_lb, g_lb + 128, g_lb + 256, h_lb, h_lb + 128, r_lb, r_lb + 128};

  float* ws = (float*)d_ws;
  float* qb  = ws;                 // 7 BANDE   (later: x)
  float* kb  = qb + 7 * BANDE;     // 7 BANDE   (later: xn)
  float* vb  = kb + 7 * BANDE;     // 7 BANDE   (later: gate, 3 used)
  float* ob  = vb + 7 * BANDE;     // 7 BANDE   (later: y)
  float* hid = ob + 7 * BANDE;     // 8 BANDE   (later: info 6 + bridge 1)
  float* bbias = hid + 8 * BANDE;  // 128
  float* xb = qb;
  float* xnb = kb;
  float* gateb = vb;
  float* yb = ob;
  float* info = hid;
  float* bridge = hid + 6 * BANDE;

  auto LRB = [&](RB& r, int NC, int gy, int Z) {
    dim3 grid(MBAND / 64, gy, Z);
    switch (NC) {
      case 2: gemm_rb<2><<<grid, dim3(256), 0, stream>>>(r); break;
      case 3: gemm_rb<3><<<grid, dim3(256), 0, stream>>>(r); break;
      case 4: gemm_rb<4><<<grid, dim3(256), 0, stream>>>(r); break;
      case 6: gemm_rb<6><<<grid, dim3(256), 0, stream>>>(r); break;
    }
  };

  // ---- 1. QKV fused: one dispatch, NC=6 (3 weights x 2 cols), Z=7 ----
  {
    RB r{};
    r.A = bands;
    for (int z = 0; z < 7; ++z) {
      r.Aoffz[z] = z * BANDE; r.Woffz[z] = (size_t)z * 16384;
      r.boffz[z] = (size_t)z * 128; r.Ooffz[z] = z * BANDE;
    }
    const float* W3[3] = {Wq, Wk, Wv};
    const float* b3[3] = {bq, bk, bv};
    float* o3[3] = {qb, kb, vb};
    for (int c = 0; c < 6; ++c) {
      int wsel = c >> 1, col = (c & 1) * 64;
      r.Wc[c] = W3[wsel] + col; r.biasc[c] = b3[wsel] + col; r.Oc[c] = o3[wsel] + col;
    }
    r.K = 128; r.WS = 128; r.OS = 128; r.op = 0;
    LRB(r, 6, 1, 7);
  }

  // ---- 2. attention ----
  attn_kernel<<<dim3(NBAND * 256), dim3(256), 0, stream>>>(qb, kb, vb, ob);

  // ---- 3. x = bands + o @ Wo + bo ----
  {
    RB r{};
    r.A = ob;
    for (int z = 0; z < 7; ++z) {
      r.Aoffz[z] = z * BANDE; r.Woffz[z] = (size_t)z * 16384;
      r.boffz[z] = (size_t)z * 128; r.roffz[z] = z * BANDE; r.Ooffz[z] = z * BANDE;
    }
    for (int c = 0; c < 2; ++c) {
      int col = c * 64;
      r.Wc[c] = Wo + col; r.biasc[c] = bo + col; r.Rc[c] = bands + col; r.Oc[c] = xb + col;
    }
    r.K = 128; r.WS = 128; r.OS = 128; r.op = 3;
    LRB(r, 2, 1, 7);
  }

  // ---- 4. LN ----
  {
    LNA p{};
    p.x = xb; p.xn = xnb;
    for (int n = 0; n < 7; ++n) { p.ls[n] = lsP[n]; p.lb[n] = lbP[n]; }
    ln_kernel<<<dim3(NBAND * MBAND / 4), dim3(256), 0, stream>>>(p);
  }

  // ---- 5. geo gates ----
  {
    RB r{};
    r.A = xb;
    for (int z = 0; z < 3; ++z) {
      r.Aoffz[z] = z * BANDE; r.Woffz[z] = (size_t)z * 16384;
      r.boffz[z] = (size_t)z * 128; r.Ooffz[z] = z * BANDE;
    }
    for (int c = 0; c < 2; ++c) {
      int col = c * 64;
      r.Wc[c] = g_wg + col; r.biasc[c] = g_bg + col; r.Oc[c] = gateb + col;
    }
    r.K = 128; r.WS = 128; r.OS = 128; r.op = 2;
    LRB(r, 2, 1, 3);
  }

  // ---- 6-7. MLP per group ----
  struct Grp { int base, cnt, N1; const float *w1, *b1, *w2, *b2; };
  const Grp grps[3] = {
    {0, 3, 256, g_w1, g_b1, g_w2, g_b2},
    {3, 2, 384, h_w1, h_b1, h_w2, h_b2},
    {5, 2, 512, r_w1, r_b1, r_w2, r_b2},
  };
  for (int gi = 0; gi < 3; ++gi) {
    const Grp& G = grps[gi];
    size_t hstride = (size_t)MBAND * G.N1;
    {  // hidden = gelu(xn @ w1 + b1)
      RB r{};
      r.A = xnb;
      for (int z = 0; z < G.cnt; ++z) {
        r.Aoffz[z] = (size_t)(G.base + z) * BANDE;
        r.Woffz[z] = (size_t)z * 128 * G.N1;
        r.boffz[z] = (size_t)z * G.N1;
        r.Ooffz[z] = z * hstride;
      }
      int tot = G.N1 / 64;                 // total chunks: 4, 6, 8
      int NC = (tot == 4) ? 4 : (tot == 6 ? 3 : 4);
      int gy = tot / NC;
      for (int cc = 0; cc < tot; ++cc) {
        r.Wc[cc] = G.w1 + cc * 64; r.biasc[cc] = G.b1 + cc * 64; r.Oc[cc] = hid + cc * 64;
      }
      r.K = 128; r.WS = G.N1; r.OS = G.N1; r.op = 1;
      LRB(r, NC, gy, G.cnt);
    }
    {  // y = x + [gate]*(hid @ w2 + b2)
      RB r{};
      r.A = hid;
      for (int z = 0; z < G.cnt; ++z) {
        r.Aoffz[z] = z * hstride;
        r.Woffz[z] = (size_t)z * G.N1 * 128;
        r.boffz[z] = (size_t)z * 128;
        r.roffz[z] = z * BANDE;
        r.eoffz[z] = z * BANDE;
        r.Ooffz[z] = z * BANDE;
      }
      for (int c = 0; c < 2; ++c) {
        int col = c * 64;
        r.Wc[c] = G.w2 + col; r.biasc[c] = G.b2 + col;
        r.Rc[c] = xb + (size_t)G.base * BANDE + col;
        r.Ec[c] = (gi == 0) ? gateb + col : nullptr;
        r.Oc[c] = yb + (size_t)G.base * BANDE + col;
      }
      r.K = G.N1; r.WS = 128; r.OS = 128; r.op = 5;
      LRB(r, 2, 1, G.cnt);
    }
  }

  // ---- 8. info ----
  {
    RB r{};
    r.A = yb;
    for (int z = 0; z < 6; ++z) {
      int t = (z < 3) ? z : z + 1;
      int src = 6 - t;
      int i = (t < 3) ? t : 6 - t;
      r.Aoffz[z] = (size_t)src * BANDE; r.Woffz[z] = (size_t)i * 16384;
      r.boffz[z] = (size_t)i * 128; r.Ooffz[z] = (size_t)z * BANDE;
    }
    for (int c = 0; c < 2; ++c) {
      int col = c * 64;
      r.Wc[c] = wp_w + col; r.biasc[c] = wp_b + col; r.Oc[c] = info + col;
    }
    r.K = 128; r.WS = 128; r.OS = 128; r.op = 0;
    LRB(r, 2, 1, 6);
  }

  // ---- 9. final gates (2-part K) ----
  {
    RB r{};
    r.A = yb; r.A2 = info;
    for (int z = 0; z < 6; ++z) {
      int t = (z < 3) ? z : z + 1;
      int i = (t < 3) ? t : 6 - t;
      r.Aoffz[z] = (size_t)t * BANDE; r.A2offz[z] = (size_t)z * BANDE;
      r.Woffz[z] = (size_t)i * 32768; r.boffz[z] = (size_t)i * 128;
      r.roffz[z] = (size_t)t * BANDE; r.eoffz[z] = (size_t)z * BANDE;
      r.Ooffz[z] = (size_t)t * BANDE;
    }
    for (int c = 0; c < 2; ++c) {
      int col = c * 64;
      r.Wc[c] = wg_w + col; r.W2c[c] = wg_w + 16384 + col;
      r.biasc[c] = wg_b + col; r.Rc[c] = yb + col; r.Ec[c] = info + col;
      r.Oc[c] = out + col;
    }
    r.K = 128; r.WS = 128; r.OS = 128; r.op = 4;
    LRB(r, 2, 1, 6);
  }

  // ---- 10. bridge ----
  bias6_kernel<<<dim3(1), dim3(128), 0, stream>>>(br_b, bbias);
  bridge_kernel<<<dim3(MBAND / 64, 2), dim3(256), 0, stream>>>(yb, br_w, bbias, bridge);

  // ---- 11. band-3 final (2-part) ----
  {
    RB r{};
    r.A = yb; r.A2 = bridge;
    r.Aoffz[0] = 3 * BANDE; r.A2offz[0] = 0;
    for (int c = 0; c < 2; ++c) {
      int col = c * 64;
      r.Wc[c] = bg_w + col; r.W2c[c] = bg_w + 16384 + col;
      r.biasc[c] = bg_b + col;
      r.Rc[c] = yb + 3 * BANDE + col;
      r.Ec[c] = bridge + col;
      r.Oc[c] = out + 3 * BANDE + col;
    }
    r.K = 128; r.WS = 128; r.OS = 128; r.op = 4;
    LRB(r, 2, 1, 1);
  }
}

// Round 8
// 424.711 us; speedup vs baseline: 1.9678x; 1.9678x over previous
//
#include <hip/hip_runtime.h>
#include <hip/hip_bf16.h>

#define NBAND 7
#define BBATCH 16
#define TSEQ 512
#define DMODEL 128
#define MBAND (BBATCH * TSEQ)               // 8192 rows per band
#define BANDE ((size_t)MBAND * DMODEL)      // 1,048,576 elements per band

typedef __attribute__((ext_vector_type(8))) short short8;
typedef __attribute__((ext_vector_type(4))) float f32x4;

__device__ __forceinline__ unsigned short f2bf(float x) {
  unsigned u = __float_as_uint(x);
  unsigned r = u + 0x7FFF + ((u >> 16) & 1);   // RNE
  return (unsigned short)(r >> 16);
}
__device__ __forceinline__ unsigned pack2(float a, float b) {
  return (unsigned)f2bf(a) | ((unsigned)f2bf(b) << 16);
}

// ---------------------------------------------------------------------------
// MFMA part: acc[2][2] (+=) A(64xK fp32) @ W(KxN fp32), 64x64 tile at (m0,n0).
// 256 threads = 4 waves 2x2; per wave 32x32 via 2x2 mfma_f32_16x16x32_bf16.
// LDS 10 KB/buffer-pair; high occupancy is this kernel's latency hiding.
// ---------------------------------------------------------------------------
__device__ __forceinline__ void mfma_part(const float* __restrict__ A,
                                          const float* __restrict__ W,
                                          int K, int N, int m0, int n0, int tid,
                                          unsigned short (*As)[40],
                                          unsigned short (*Bs)[40],
                                          f32x4 acc[2][2]) {
  const int lane = tid & 63;
  const int wv = tid >> 6;
  const int wr = wv >> 1, wc = wv & 1;
  const int lr = lane & 15, k8 = lane >> 4;

  for (int k0 = 0; k0 < K; k0 += 32) {
    #pragma unroll
    for (int it = 0; it < 2; ++it) {
      int t = tid + it * 256;
      int m = t >> 3, kq = (t & 7) << 2;
      const float4 v = *(const float4*)&A[(size_t)(m0 + m) * K + k0 + kq];
      *(unsigned*)&As[m][kq]     = pack2(v.x, v.y);
      *(unsigned*)&As[m][kq + 2] = pack2(v.z, v.w);
    }
    #pragma unroll
    for (int it = 0; it < 2; ++it) {
      int t = tid + it * 256;
      int k = t >> 4, nq = (t & 15) << 2;
      const float4 v = *(const float4*)&W[(size_t)(k0 + k) * N + n0 + nq];
      Bs[nq + 0][k] = f2bf(v.x); Bs[nq + 1][k] = f2bf(v.y);
      Bs[nq + 2][k] = f2bf(v.z); Bs[nq + 3][k] = f2bf(v.w);
    }
    __syncthreads();
    short8 a0 = *(const short8*)&As[wr * 32 + lr][k8 * 8];
    short8 a1 = *(const short8*)&As[wr * 32 + 16 + lr][k8 * 8];
    short8 b0 = *(const short8*)&Bs[wc * 32 + lr][k8 * 8];
    short8 b1 = *(const short8*)&Bs[wc * 32 + 16 + lr][k8 * 8];
    acc[0][0] = __builtin_amdgcn_mfma_f32_16x16x32_bf16(a0, b0, acc[0][0], 0, 0, 0);
    acc[0][1] = __builtin_amdgcn_mfma_f32_16x16x32_bf16(a0, b1, acc[0][1], 0, 0, 0);
    acc[1][0] = __builtin_amdgcn_mfma_f32_16x16x32_bf16(a1, b0, acc[1][0], 0, 0, 0);
    acc[1][1] = __builtin_amdgcn_mfma_f32_16x16x32_bf16(a1, b1, acc[1][1], 0, 0, 0);
    __syncthreads();
  }
}

// ---------------------------------------------------------------------------
// Batched GEMM over blockIdx.z:  C_z = epi( A_z@W_z [+ A2_z@W2_z] + b_z )
// ---------------------------------------------------------------------------
struct PArgs {
  const float *A, *W, *bias, *A2, *W2, *resid, *extra;
  float* O;
  size_t Aoff[8], Woff[8], boff[8], A2off[8], W2off[8], roff[8], eoff[8], Ooff[8];
  int K, N, op;     // 0 store 1 gelu 2 sigmoid 3 resid+ 4 resid+sig(v)*extra 5 resid+extra*v
};

__global__ __launch_bounds__(256) void gemm_b(PArgs p) {
  __shared__ __align__(16) unsigned short As[64][40];
  __shared__ __align__(16) unsigned short Bs[64][40];
  const int z = blockIdx.z;
  const int m0 = blockIdx.x * 64, n0 = blockIdx.y * 64;
  const int tid = threadIdx.x;
  f32x4 acc[2][2] = {};

  mfma_part(p.A + p.Aoff[z], p.W + p.Woff[z], p.K, p.N, m0, n0, tid, As, Bs, acc);
  if (p.A2)
    mfma_part(p.A2 + p.A2off[z], p.W2 + p.W2off[z], p.K, p.N, m0, n0, tid, As, Bs, acc);

  const float* bias  = p.bias  ? p.bias  + p.boff[z] : nullptr;
  const float* resid = p.resid ? p.resid + p.roff[z] : nullptr;
  const float* extra = p.extra ? p.extra + p.eoff[z] : nullptr;
  float* O = p.O + p.Ooff[z];

  const int lane = tid & 63;
  const int wv = tid >> 6;
  const int wr = wv >> 1, wc = wv & 1;
  const int lr = lane & 15, lg = lane >> 4;

  #pragma unroll
  for (int i = 0; i < 2; ++i) {
    #pragma unroll
    for (int j = 0; j < 2; ++j) {
      #pragma unroll
      for (int r = 0; r < 4; ++r) {
        int m = m0 + wr * 32 + i * 16 + lg * 4 + r;
        int n = n0 + wc * 32 + j * 16 + lr;
        float v = acc[i][j][r];
        if (bias) v += bias[n];
        size_t idx = (size_t)m * p.N + n;
        switch (p.op) {
          case 0: O[idx] = v; break;
          case 1: O[idx] = 0.5f * v * (1.f + erff(v * 0.70710678118654752f)); break;
          case 2: O[idx] = 1.f / (1.f + __expf(-v)); break;
          case 3: O[idx] = resid[idx] + v; break;
          case 4: {
            float gate = 1.f / (1.f + __expf(-v));
            O[idx] = resid[idx] + gate * extra[idx];
          } break;
          case 5: {
            float gm = extra ? extra[idx] : 1.f;
            O[idx] = resid[idx] + gm * v;
          } break;
        }
      }
    }
  }
}

// 6-part bridge: O = (sum_j y[bl_j] @ br_w[j]) / 6 + bbias   (bbias = sum(br_b)/6)
__global__ __launch_bounds__(256) void bridge_kernel(const float* __restrict__ yb,
                                                     const float* __restrict__ br_w,
                                                     const float* __restrict__ bbias,
                                                     float* __restrict__ O) {
  __shared__ __align__(16) unsigned short As[64][40];
  __shared__ __align__(16) unsigned short Bs[64][40];
  const int m0 = blockIdx.x * 64, n0 = blockIdx.y * 64;
  const int tid = threadIdx.x;
  f32x4 acc[2][2] = {};
  const int bl[6] = {0, 1, 2, 4, 5, 6};
  for (int j = 0; j < 6; ++j)
    mfma_part(yb + (size_t)bl[j] * BANDE, br_w + j * 16384, 128, 128, m0, n0, tid, As, Bs, acc);

  const int lane = tid & 63;
  const int wv = tid >> 6;
  const int wr = wv >> 1, wc = wv & 1;
  const int lr = lane & 15, lg = lane >> 4;
  #pragma unroll
  for (int i = 0; i < 2; ++i)
    #pragma unroll
    for (int j = 0; j < 2; ++j)
      #pragma unroll
      for (int r = 0; r < 4; ++r) {
        int m = m0 + wr * 32 + i * 16 + lg * 4 + r;
        int n = n0 + wc * 32 + j * 16 + lr;
        O[(size_t)m * 128 + n] = acc[i][j][r] * (1.f / 6.f) + bbias[n];
      }
}

// ---------------------------------------------------------------------------
// MFMA flash attention, causal. H=2, HD=64, T=512, multi-band.
// Conflict-free staging: Q/K packed u32 row writes; V transposed via
// dword-packed key-pair writes (<=2-way banks).
// ---------------------------------------------------------------------------
__global__ __launch_bounds__(256) void attn_kernel(const float* __restrict__ q,
                                                   const float* __restrict__ k,
                                                   const float* __restrict__ v,
                                                   float* __restrict__ o) {
  const int band = blockIdx.x >> 8;
  const int rest = blockIdx.x & 255;
  const int qt = rest & 7;
  const int bh = rest >> 3;
  const int h  = bh & 1;
  const int b  = bh >> 1;
  const size_t rowbase = ((size_t)band * BBATCH + b) * TSEQ;

  const int tid  = threadIdx.x;
  const int w    = tid >> 6;
  const int lane = tid & 63;
  const int lr   = lane & 15;
  const int lg   = lane >> 4;

  __shared__ __align__(16) unsigned short Qs[64][72];
  __shared__ __align__(16) unsigned short Ks[64][72];          // [key][dim]
  __shared__ __align__(16) unsigned short Vs[64][72];          // [dim][key]
  __shared__ __align__(16) unsigned short Ps[4][16][72];       // per-wave P

  #pragma unroll
  for (int it = 0; it < 4; ++it) {
    int idx = tid + it * 256;
    int r = idx >> 4, dq = (idx & 15) << 2;
    const float4 val = *(const float4*)&q[(rowbase + qt * 64 + r) * DMODEL + h * 64 + dq];
    *(unsigned*)&Qs[r][dq]     = pack2(val.x * 0.125f, val.y * 0.125f);
    *(unsigned*)&Qs[r][dq + 2] = pack2(val.z * 0.125f, val.w * 0.125f);
  }

  f32x4 oacc[4] = {};
  float m[4], l[4];
  #pragma unroll
  for (int r = 0; r < 4; ++r) { m[r] = -1e30f; l[r] = 0.f; }

  for (int kt = 0; kt <= qt; ++kt) {
    __syncthreads();
    #pragma unroll
    for (int it = 0; it < 4; ++it) {       // K: [key][dim], packed row writes
      int idx = tid + it * 256;
      int r = idx >> 4, dq = (idx & 15) << 2;
      const float4 kv = *(const float4*)&k[(rowbase + kt * 64 + r) * DMODEL + h * 64 + dq];
      *(unsigned*)&Ks[r][dq]     = pack2(kv.x, kv.y);
      *(unsigned*)&Ks[r][dq + 2] = pack2(kv.z, kv.w);
    }
    #pragma unroll
    for (int it = 0; it < 2; ++it) {       // V: [dim][key], key-pair packed
      int idx = tid + it * 256;            // 0..511
      int kp = idx >> 4;                   // key pair 0..31
      int d0 = (idx & 15) << 2;
      size_t g0 = (rowbase + kt * 64 + 2 * kp) * DMODEL + h * 64 + d0;
      const float4 va = *(const float4*)&v[g0];
      const float4 vb = *(const float4*)&v[g0 + DMODEL];
      *(unsigned*)&Vs[d0 + 0][2 * kp] = pack2(va.x, vb.x);
      *(unsigned*)&Vs[d0 + 1][2 * kp] = pack2(va.y, vb.y);
      *(unsigned*)&Vs[d0 + 2][2 * kp] = pack2(va.z, vb.z);
      *(unsigned*)&Vs[d0 + 3][2 * kp] = pack2(va.w, vb.w);
    }
    __syncthreads();

    // ---- QK^T
    f32x4 s[4] = {};
    #pragma unroll
    for (int c = 0; c < 2; ++c) {
      short8 a = *(const short8*)&Qs[w * 16 + lr][c * 32 + lg * 8];
      #pragma unroll
      for (int j = 0; j < 4; ++j) {
        short8 bb = *(const short8*)&Ks[j * 16 + lr][c * 32 + lg * 8];
        s[j] = __builtin_amdgcn_mfma_f32_16x16x32_bf16(a, bb, s[j], 0, 0, 0);
      }
    }

    if (kt == qt) {
      #pragma unroll
      for (int j = 0; j < 4; ++j)
        #pragma unroll
        for (int r = 0; r < 4; ++r) {
          int row = w * 16 + lg * 4 + r;
          int col = j * 16 + lr;
          if (col > row) s[j][r] = -1e30f;
        }
    }

    // ---- online softmax
    float mx[4], al[4];
    #pragma unroll
    for (int r = 0; r < 4; ++r)
      mx[r] = fmaxf(fmaxf(s[0][r], s[1][r]), fmaxf(s[2][r], s[3][r]));
    #pragma unroll
    for (int off = 1; off <= 8; off <<= 1)
      #pragma unroll
      for (int r = 0; r < 4; ++r)
        mx[r] = fmaxf(mx[r], __shfl_xor(mx[r], off));
    #pragma unroll
    for (int r = 0; r < 4; ++r) {
      float mn = fmaxf(m[r], mx[r]);
      al[r] = __expf(m[r] - mn);
      m[r] = mn;
    }
    float rs[4] = {0.f, 0.f, 0.f, 0.f};
    #pragma unroll
    for (int j = 0; j < 4; ++j)
      #pragma unroll
      for (int r = 0; r < 4; ++r) {
        float pe = __expf(s[j][r] - m[r]);
        s[j][r] = pe;
        rs[r] += pe;
      }
    #pragma unroll
    for (int off = 1; off <= 8; off <<= 1)
      #pragma unroll
      for (int r = 0; r < 4; ++r)
        rs[r] += __shfl_xor(rs[r], off);
    #pragma unroll
    for (int r = 0; r < 4; ++r) l[r] = l[r] * al[r] + rs[r];

    #pragma unroll
    for (int j = 0; j < 4; ++j)
      #pragma unroll
      for (int r = 0; r < 4; ++r)
        oacc[j][r] *= al[r];

    // ---- P transpose via per-wave LDS
    #pragma unroll
    for (int j = 0; j < 4; ++j)
      #pragma unroll
      for (int r = 0; r < 4; ++r)
        Ps[w][lg * 4 + r][j * 16 + lr] = f2bf(s[j][r]);

    // ---- PV
    #pragma unroll
    for (int c = 0; c < 2; ++c) {
      short8 a = *(const short8*)&Ps[w][lr][c * 32 + lg * 8];
      #pragma unroll
      for (int j = 0; j < 4; ++j) {
        short8 bb = *(const short8*)&Vs[j * 16 + lr][c * 32 + lg * 8];
        oacc[j] = __builtin_amdgcn_mfma_f32_16x16x32_bf16(a, bb, oacc[j], 0, 0, 0);
      }
    }
  }

  float inv[4];
  #pragma unroll
  for (int r = 0; r < 4; ++r) inv[r] = 1.f / l[r];
  #pragma unroll
  for (int j = 0; j < 4; ++j)
    #pragma unroll
    for (int r = 0; r < 4; ++r) {
      size_t row = rowbase + qt * 64 + w * 16 + lg * 4 + r;
      o[row * DMODEL + h * 64 + j * 16 + lr] = oacc[j][r] * inv[r];
    }
}

// ---------------------------------------------------------------------------
struct LNA {
  const float* x;
  float* xn;
  const float* ls[7];
  const float* lb[7];
};

__global__ __launch_bounds__(256) void ln_kernel(LNA p) {
  const int tid = threadIdx.x;
  const int rr = tid >> 6, lane = tid & 63;
  const size_t row = (size_t)blockIdx.x * 4 + rr;
  const float* xp = p.x + row * DMODEL;
  float a = xp[lane], b = xp[lane + 64];
  float s = a + b;
  #pragma unroll
  for (int off = 32; off; off >>= 1) s += __shfl_xor(s, off);
  float mean = s * (1.f / 128.f);
  float da = a - mean, db = b - mean;
  float vs = da * da + db * db;
  #pragma unroll
  for (int off = 32; off; off >>= 1) vs += __shfl_xor(vs, off);
  float rstd = rsqrtf(vs * (1.f / 128.f) + 1e-5f);
  int band = (int)(row >> 13);
  const float* ls = p.ls[band];
  const float* lb = p.lb[band];
  float* op = p.xn + row * DMODEL;
  op[lane]      = da * rstd * ls[lane]      + lb[lane];
  op[lane + 64] = db * rstd * ls[lane + 64] + lb[lane + 64];
}

__global__ void bias6_kernel(const float* __restrict__ br_b, float* __restrict__ out) {
  int d = threadIdx.x;
  float s = 0.f;
  #pragma unroll
  for (int j = 0; j < 6; ++j) s += br_b[j * 128 + d];
  out[d] = s * (1.f / 6.f);
}

// ---------------------------------------------------------------------------
extern "C" void kernel_launch(void* const* d_in, const int* in_sizes, int n_in,
                              void* d_out, int out_size, void* d_ws, size_t ws_size,
                              hipStream_t stream) {
  bool dict = (in_sizes[2] != 896);
  const float* bands = (const float*)d_in[0];
  const float* Wq = (const float*)d_in[1];
  const float *Wk, *Wv, *Wo, *bq, *bk, *bv, *bo;
  if (dict) {
    Wk = (const float*)d_in[2]; Wv = (const float*)d_in[3]; Wo = (const float*)d_in[4];
    bq = (const float*)d_in[5]; bk = (const float*)d_in[6];
    bv = (const float*)d_in[7]; bo = (const float*)d_in[8];
  } else {
    bq = (const float*)d_in[2]; Wk = (const float*)d_in[3]; bk = (const float*)d_in[4];
    Wv = (const float*)d_in[5]; bv = (const float*)d_in[6];
    Wo = (const float*)d_in[7]; bo = (const float*)d_in[8];
  }
  const float* g_ls = (const float*)d_in[9];
  const float* g_lb = (const float*)d_in[10];
  const float* g_w1 = (const float*)d_in[11];
  const float* g_b1 = (const float*)d_in[12];
  const float* g_w2 = (const float*)d_in[13];
  const float* g_b2 = (const float*)d_in[14];
  const float* g_wg = (const float*)d_in[15];
  const float* g_bg = (const float*)d_in[16];
  const float* h_ls = (const float*)d_in[17];
  const float* h_lb = (const float*)d_in[18];
  const float* h_w1 = (const float*)d_in[19];
  const float* h_b1 = (const float*)d_in[20];
  const float* h_w2 = (const float*)d_in[21];
  const float* h_b2 = (const float*)d_in[22];
  const float* r_ls = (const float*)d_in[23];
  const float* r_lb = (const float*)d_in[24];
  const float* r_w1 = (const float*)d_in[25];
  const float* r_b1 = (const float*)d_in[26];
  const float* r_w2 = (const float*)d_in[27];
  const float* r_b2 = (const float*)d_in[28];
  const float* wp_w = (const float*)d_in[29];
  const float* wp_b = (const float*)d_in[30];
  const float* wg_w = (const float*)d_in[31];
  const float* wg_b = (const float*)d_in[32];
  const float* br_w = (const float*)d_in[33];
  const float* br_b = (const float*)d_in[34];
  const float* bg_w = (const float*)d_in[35];
  const float* bg_b = (const float*)d_in[36];
  float* out = (float*)d_out;

  const int hN[7] = {256, 256, 256, 384, 384, 512, 512};
  const float* lsP[7] = {g_ls, g_ls + 128, g_ls + 256, h_ls, h_ls + 128, r_ls, r_ls + 128};
  const float* lbP[7] = {g_lb, g_lb + 128, g_lb + 256, h_lb, h_lb + 128, r_lb, r_lb + 128};
  const float* w1p[7] = {g_w1, g_w1 + 32768, g_w1 + 65536,
                         h_w1, h_w1 + 49152, r_w1, r_w1 + 65536};
  const float* b1p[7] = {g_b1, g_b1 + 256, g_b1 + 512,
                         h_b1, h_b1 + 384, r_b1, r_b1 + 512};
  const float* w2p[7] = {g_w2, g_w2 + 32768, g_w2 + 65536,
                         h_w2, h_w2 + 49152, r_w2, r_w2 + 65536};
  const float* b2p[7] = {g_b2, g_b2 + 128, g_b2 + 256,
                         h_b2, h_b2 + 128, r_b2, r_b2 + 128};

  auto LP = [&](PArgs& p, int Z) {
    dim3 grid(MBAND / 64, p.N / 64, Z);
    gemm_b<<<grid, dim3(256), 0, stream>>>(p);
  };

  float* ws = (float*)d_ws;
  float* qb  = ws;                 // 7 BANDE   (later: x)
  float* kb  = qb + 7 * BANDE;     // 7 BANDE   (later: xn)
  float* vb  = kb + 7 * BANDE;     // 7 BANDE   (later: gate, 3 used)
  float* ob  = vb + 7 * BANDE;     // 7 BANDE   (later: y)
  float* hid = ob + 7 * BANDE;     // 8 BANDE   (later: info 6 + bridge 1)
  float* bbias = hid + 8 * BANDE;  // 128
  float* xb = qb;
  float* xnb = kb;
  float* gateb = vb;
  float* yb = ob;
  float* info = hid;
  float* bridge = hid + 6 * BANDE;

  // 1-3. Q/K/V projections, Z=7 each
  const float* Wqkv[3] = {Wq, Wk, Wv};
  const float* bqkv[3] = {bq, bk, bv};
  float* oqkv[3] = {qb, kb, vb};
  for (int w = 0; w < 3; ++w) {
    PArgs p{};
    p.A = bands; p.W = Wqkv[w]; p.bias = bqkv[w]; p.O = oqkv[w];
    for (int z = 0; z < 7; ++z) {
      p.Aoff[z] = z * BANDE; p.Woff[z] = (size_t)z * 16384;
      p.boff[z] = (size_t)z * 128; p.Ooff[z] = z * BANDE;
    }
    p.K = 128; p.N = 128; p.op = 0;
    LP(p, 7);
  }

  // 4. attention, all bands
  attn_kernel<<<dim3(NBAND * 256), dim3(256), 0, stream>>>(qb, kb, vb, ob);

  // 5. x = bands + o @ Wo + bo
  {
    PArgs p{};
    p.A = ob; p.W = Wo; p.bias = bo; p.resid = bands; p.O = xb;
    for (int z = 0; z < 7; ++z) {
      p.Aoff[z] = z * BANDE; p.Woff[z] = (size_t)z * 16384;
      p.boff[z] = (size_t)z * 128; p.roff[z] = z * BANDE; p.Ooff[z] = z * BANDE;
    }
    p.K = 128; p.N = 128; p.op = 3;
    LP(p, 7);
  }

  // 6. LN all bands
  {
    LNA p{};
    p.x = xb; p.xn = xnb;
    for (int n = 0; n < 7; ++n) { p.ls[n] = lsP[n]; p.lb[n] = lbP[n]; }
    ln_kernel<<<dim3(NBAND * MBAND / 4), dim3(256), 0, stream>>>(p);
  }

  // 7. geo gates, Z=3
  {
    PArgs p{};
    p.A = xb; p.W = g_wg; p.bias = g_bg; p.O = gateb;
    for (int z = 0; z < 3; ++z) {
      p.Aoff[z] = z * BANDE; p.Woff[z] = (size_t)z * 16384;
      p.boff[z] = (size_t)z * 128; p.Ooff[z] = z * BANDE;
    }
    p.K = 128; p.N = 128; p.op = 2;
    LP(p, 3);
  }

  // 8-13. MLP per group: geo(3,256) hyb(2,384) rea(2,512)
  const int gcnt[3] = {3, 2, 2};
  const int gbase[3] = {0, 3, 5};
  for (int grp = 0; grp < 3; ++grp) {
    int cnt = gcnt[grp], base = gbase[grp], N1 = hN[base];
    size_t hstride = (size_t)MBAND * N1;
    {  // hidden = gelu(xn @ w1 + b1)
      PArgs p{};
      p.A = xnb; p.W = w1p[base]; p.bias = b1p[base]; p.O = hid;
      for (int z = 0; z < cnt; ++z) {
        p.Aoff[z] = (size_t)(base + z) * BANDE;
        p.Woff[z] = (size_t)(w1p[base + z] - w1p[base]);
        p.boff[z] = (size_t)(b1p[base + z] - b1p[base]);
        p.Ooff[z] = z * hstride;
      }
      p.K = 128; p.N = N1; p.op = 1;
      LP(p, cnt);
    }
    {  // y = x + [gate]*(hid @ w2 + b2)
      PArgs p{};
      p.A = hid; p.W = w2p[base]; p.bias = b2p[base];
      p.resid = xb; p.O = yb;
      if (grp == 0) p.extra = gateb;
      for (int z = 0; z < cnt; ++z) {
        p.Aoff[z] = z * hstride;
        p.Woff[z] = (size_t)(w2p[base + z] - w2p[base]);
        p.boff[z] = (size_t)(b2p[base + z] - b2p[base]);
        p.roff[z] = (size_t)(base + z) * BANDE;
        p.eoff[z] = z * BANDE;
        p.Ooff[z] = (size_t)(base + z) * BANDE;
      }
      p.K = N1; p.N = 128; p.op = 5;
      LP(p, cnt);
    }
  }

  // 14. info, Z=6
  {
    PArgs p{};
    p.A = yb; p.W = wp_w; p.bias = wp_b; p.O = info;
    for (int z = 0; z < 6; ++z) {
      int t = (z < 3) ? z : z + 1;
      int src = 6 - t;
      int i = (t < 3) ? t : 6 - t;
      p.Aoff[z] = (size_t)src * BANDE; p.Woff[z] = (size_t)i * 16384;
      p.boff[z] = (size_t)i * 128; p.Ooff[z] = (size_t)z * BANDE;
    }
    p.K = 128; p.N = 128; p.op = 0;
    LP(p, 6);
  }

  // 15. final gates for 6 targets (2-part K)
  {
    PArgs p{};
    p.A = yb; p.W = wg_w; p.A2 = info; p.W2 = wg_w;
    p.bias = wg_b; p.resid = yb; p.extra = info; p.O = out;
    for (int z = 0; z < 6; ++z) {
      int t = (z < 3) ? z : z + 1;
      int i = (t < 3) ? t : 6 - t;
      p.Aoff[z] = (size_t)t * BANDE;  p.Woff[z] = (size_t)i * 32768;
      p.A2off[z] = (size_t)z * BANDE; p.W2off[z] = (size_t)i * 32768 + 16384;
      p.boff[z] = (size_t)i * 128;
      p.roff[z] = (size_t)t * BANDE;  p.eoff[z] = (size_t)z * BANDE;
      p.Ooff[z] = (size_t)t * BANDE;
    }
    p.K = 128; p.N = 128; p.op = 4;
    LP(p, 6);
  }

  // 16-17. bridge
  bias6_kernel<<<dim3(1), dim3(128), 0, stream>>>(br_b, bbias);
  bridge_kernel<<<dim3(MBAND / 64, 2), dim3(256), 0, stream>>>(yb, br_w, bbias, bridge);

  // 18. band-3 final (2-part)
  {
    PArgs p{};
    p.A = yb; p.W = bg_w; p.A2 = bridge; p.W2 = bg_w;
    p.bias = bg_b; p.resid = yb; p.extra = bridge; p.O = out;
    p.Aoff[0] = 3 * BANDE; p.Woff[0] = 0;
    p.A2off[0] = 0; p.W2off[0] = 16384;
    p.boff[0] = 0; p.roff[0] = 3 * BANDE; p.eoff[0] = 0; p.Ooff[0] = 3 * BANDE;
    p.K = 128; p.N = 128; p.op = 4;
    LP(p, 1);
  }
}

// Round 9
// 372.337 us; speedup vs baseline: 2.2445x; 1.1407x over previous
//
#include <hip/hip_runtime.h>
#include <hip/hip_bf16.h>

#define NBAND 7
#define BBATCH 16
#define TSEQ 512
#define DMODEL 128
#define MBAND (BBATCH * TSEQ)               // 8192 rows per band
#define BANDE ((size_t)MBAND * DMODEL)      // 1,048,576 elements per band

typedef __attribute__((ext_vector_type(8))) short short8;
typedef __attribute__((ext_vector_type(4))) float f32x4;
typedef unsigned int u32;
typedef unsigned short u16;

__device__ __forceinline__ u16 f2bf(float x) {
  unsigned u = __float_as_uint(x);
  unsigned r = u + 0x7FFF + ((u >> 16) & 1);   // RNE
  return (u16)(r >> 16);
}
__device__ __forceinline__ u32 pack2(float a, float b) {
  return (u32)f2bf(a) | ((u32)f2bf(b) << 16);
}
__device__ __forceinline__ float b2f(u16 h) {
  return __uint_as_float((u32)h << 16);
}

// ---------------------------------------------------------------------------
// MFMA part, bf16 A source: acc[2][2] += A(64xK bf16) @ W(KxN fp32),
// 64x64 tile at (m0,n0). 256 thr = 4 waves 2x2, 32x32/wave, K-step 32.
// ---------------------------------------------------------------------------
__device__ __forceinline__ void mfma_part_h(const u16* __restrict__ A,
                                            const float* __restrict__ W,
                                            int K, int N, int m0, int n0, int tid,
                                            u16 (*As)[40], u16 (*Bs)[40],
                                            f32x4 acc[2][2]) {
  const int lane = tid & 63;
  const int wv = tid >> 6;
  const int wr = wv >> 1, wc = wv & 1;
  const int lr = lane & 15, k8 = lane >> 4;

  for (int k0 = 0; k0 < K; k0 += 32) {
    {   // stage A: 64 rows x 32 k bf16 = 2048 u16; one short8 per thread
      int row = tid >> 2, kq = (tid & 3) << 3;
      *(short8*)&As[row][kq] =
          *(const short8*)&A[(size_t)(m0 + row) * K + k0 + kq];
    }
    #pragma unroll
    for (int it = 0; it < 2; ++it) {   // stage B: 32 k x 64 n (fp32 W -> bf16 T)
      int t = tid + it * 256;
      int k = t >> 4, nq = (t & 15) << 2;
      const float4 v = *(const float4*)&W[(size_t)(k0 + k) * N + n0 + nq];
      Bs[nq + 0][k] = f2bf(v.x); Bs[nq + 1][k] = f2bf(v.y);
      Bs[nq + 2][k] = f2bf(v.z); Bs[nq + 3][k] = f2bf(v.w);
    }
    __syncthreads();
    short8 a0 = *(const short8*)&As[wr * 32 + lr][k8 * 8];
    short8 a1 = *(const short8*)&As[wr * 32 + 16 + lr][k8 * 8];
    short8 b0 = *(const short8*)&Bs[wc * 32 + lr][k8 * 8];
    short8 b1 = *(const short8*)&Bs[wc * 32 + 16 + lr][k8 * 8];
    acc[0][0] = __builtin_amdgcn_mfma_f32_16x16x32_bf16(a0, b0, acc[0][0], 0, 0, 0);
    acc[0][1] = __builtin_amdgcn_mfma_f32_16x16x32_bf16(a0, b1, acc[0][1], 0, 0, 0);
    acc[1][0] = __builtin_amdgcn_mfma_f32_16x16x32_bf16(a1, b0, acc[1][0], 0, 0, 0);
    acc[1][1] = __builtin_amdgcn_mfma_f32_16x16x32_bf16(a1, b1, acc[1][1], 0, 0, 0);
    __syncthreads();
  }
}

// ---------------------------------------------------------------------------
// Batched GEMM over blockIdx.z (bf16 activations, fp32 weights).
// ---------------------------------------------------------------------------
struct PArgs {
  const u16 *A, *A2;
  const float *W, *W2, *bias;
  const float* residF;          // op3 (fp32 residual = original input)
  const u16 *residH, *extraH;   // op4/5 (bf16 residual/extra)
  float* OF;                    // op4 output (fp32 final)
  u16* OH;                      // other outputs (bf16)
  size_t Aoff[8], Woff[8], boff[8], A2off[8], W2off[8], roff[8], eoff[8], Ooff[8];
  int K, N, op;   // 0 store 1 gelu 2 sigmoid 3 residF+ 4 residH+sig(v)*extraH->f32 5 residH+extraH*v
};

__global__ __launch_bounds__(256) void gemm_b(PArgs p) {
  __shared__ __align__(16) u16 As[64][40];
  __shared__ __align__(16) u16 Bs[64][40];
  const int z = blockIdx.z;
  const int m0 = blockIdx.x * 64, n0 = blockIdx.y * 64;
  const int tid = threadIdx.x;
  f32x4 acc[2][2] = {};

  mfma_part_h(p.A + p.Aoff[z], p.W + p.Woff[z], p.K, p.N, m0, n0, tid, As, Bs, acc);
  if (p.A2)
    mfma_part_h(p.A2 + p.A2off[z], p.W2 + p.W2off[z], p.K, p.N, m0, n0, tid, As, Bs, acc);

  const float* bias = p.bias ? p.bias + p.boff[z] : nullptr;
  const int lane = tid & 63;
  const int wv = tid >> 6;
  const int wr = wv >> 1, wc = wv & 1;
  const int lr = lane & 15, lg = lane >> 4;

  #pragma unroll
  for (int i = 0; i < 2; ++i) {
    #pragma unroll
    for (int j = 0; j < 2; ++j) {
      #pragma unroll
      for (int r = 0; r < 4; ++r) {
        int m = m0 + wr * 32 + i * 16 + lg * 4 + r;
        int n = n0 + wc * 32 + j * 16 + lr;
        float v = acc[i][j][r];
        if (bias) v += bias[n];
        size_t idx = (size_t)m * p.N + n;
        switch (p.op) {
          case 0: p.OH[p.Ooff[z] + idx] = f2bf(v); break;
          case 1: p.OH[p.Ooff[z] + idx] =
                    f2bf(0.5f * v * (1.f + erff(v * 0.70710678118654752f))); break;
          case 2: p.OH[p.Ooff[z] + idx] = f2bf(1.f / (1.f + __expf(-v))); break;
          case 3: p.OH[p.Ooff[z] + idx] =
                    f2bf(p.residF[p.roff[z] + idx] + v); break;
          case 4: {
            float gate = 1.f / (1.f + __expf(-v));
            p.OF[p.Ooff[z] + idx] = b2f(p.residH[p.roff[z] + idx]) +
                                    gate * b2f(p.extraH[p.eoff[z] + idx]);
          } break;
          case 5: {
            float gm = p.extraH ? b2f(p.extraH[p.eoff[z] + idx]) : 1.f;
            p.OH[p.Ooff[z] + idx] = f2bf(b2f(p.residH[p.roff[z] + idx]) + gm * v);
          } break;
        }
      }
    }
  }
}

// 6-part bridge: O = bf16( (sum_j y[bl_j] @ br_w[j]) / 6 + bbias )
__global__ __launch_bounds__(256) void bridge_kernel(const u16* __restrict__ yb,
                                                     const float* __restrict__ br_w,
                                                     const float* __restrict__ bbias,
                                                     u16* __restrict__ O) {
  __shared__ __align__(16) u16 As[64][40];
  __shared__ __align__(16) u16 Bs[64][40];
  const int m0 = blockIdx.x * 64, n0 = blockIdx.y * 64;
  const int tid = threadIdx.x;
  f32x4 acc[2][2] = {};
  const int bl[6] = {0, 1, 2, 4, 5, 6};
  for (int j = 0; j < 6; ++j)
    mfma_part_h(yb + (size_t)bl[j] * BANDE, br_w + j * 16384, 128, 128, m0, n0, tid, As, Bs, acc);

  const int lane = tid & 63;
  const int wv = tid >> 6;
  const int wr = wv >> 1, wc = wv & 1;
  const int lr = lane & 15, lg = lane >> 4;
  #pragma unroll
  for (int i = 0; i < 2; ++i)
    #pragma unroll
    for (int j = 0; j < 2; ++j)
      #pragma unroll
      for (int r = 0; r < 4; ++r) {
        int m = m0 + wr * 32 + i * 16 + lg * 4 + r;
        int n = n0 + wc * 32 + j * 16 + lr;
        O[(size_t)m * 128 + n] = f2bf(acc[i][j][r] * (1.f / 6.f) + bbias[n]);
      }
}

// ---------------------------------------------------------------------------
// MFMA flash attention, causal, bf16 q/k/v/o. H=2, HD=64, T=512, multi-band.
// Scale 1/8 applied post-QK^T so staging is a pure copy.
// ---------------------------------------------------------------------------
__global__ __launch_bounds__(256) void attn_kernel(const u16* __restrict__ q,
                                                   const u16* __restrict__ k,
                                                   const u16* __restrict__ v,
                                                   u16* __restrict__ o) {
  const int band = blockIdx.x >> 8;
  const int rest = blockIdx.x & 255;
  const int qt = rest & 7;
  const int bh = rest >> 3;
  const int h  = bh & 1;
  const int b  = bh >> 1;
  const size_t rowbase = ((size_t)band * BBATCH + b) * TSEQ;

  const int tid  = threadIdx.x;
  const int w    = tid >> 6;
  const int lane = tid & 63;
  const int lr   = lane & 15;
  const int lg   = lane >> 4;

  __shared__ __align__(16) u16 Qs[64][72];
  __shared__ __align__(16) u16 Ks[64][72];          // [key][dim]
  __shared__ __align__(16) u16 Vs[64][72];          // [dim][key]
  __shared__ __align__(16) u16 Ps[4][16][72];       // per-wave P

  #pragma unroll
  for (int it = 0; it < 2; ++it) {       // Q copy: 64 rows x 64 dims
    int idx = tid + it * 256;
    int r = idx >> 3, c8 = (idx & 7) << 3;
    *(short8*)&Qs[r][c8] =
        *(const short8*)&q[(rowbase + qt * 64 + r) * DMODEL + h * 64 + c8];
  }

  f32x4 oacc[4] = {};
  float m[4], l[4];
  #pragma unroll
  for (int r = 0; r < 4; ++r) { m[r] = -1e30f; l[r] = 0.f; }

  for (int kt = 0; kt <= qt; ++kt) {
    __syncthreads();
    #pragma unroll
    for (int it = 0; it < 2; ++it) {     // K copy
      int idx = tid + it * 256;
      int r = idx >> 3, c8 = (idx & 7) << 3;
      *(short8*)&Ks[r][c8] =
          *(const short8*)&k[(rowbase + kt * 64 + r) * DMODEL + h * 64 + c8];
    }
    #pragma unroll
    for (int it = 0; it < 2; ++it) {     // V transpose, key-pair merged u32 writes
      int idx = tid + it * 256;
      int kp = idx >> 4, d0 = (idx & 15) << 2;
      size_t g0 = (rowbase + kt * 64 + 2 * kp) * DMODEL + h * 64 + d0;
      u32 a0 = *(const u32*)&v[g0];
      u32 a1 = *(const u32*)&v[g0 + 2];
      u32 b0 = *(const u32*)&v[g0 + DMODEL];
      u32 b1 = *(const u32*)&v[g0 + DMODEL + 2];
      *(u32*)&Vs[d0 + 0][2 * kp] = (a0 & 0xFFFFu) | (b0 << 16);
      *(u32*)&Vs[d0 + 1][2 * kp] = (a0 >> 16) | (b0 & 0xFFFF0000u);
      *(u32*)&Vs[d0 + 2][2 * kp] = (a1 & 0xFFFFu) | (b1 << 16);
      *(u32*)&Vs[d0 + 3][2 * kp] = (a1 >> 16) | (b1 & 0xFFFF0000u);
    }
    __syncthreads();

    // ---- QK^T
    f32x4 s[4] = {};
    #pragma unroll
    for (int c = 0; c < 2; ++c) {
      short8 a = *(const short8*)&Qs[w * 16 + lr][c * 32 + lg * 8];
      #pragma unroll
      for (int j = 0; j < 4; ++j) {
        short8 bb = *(const short8*)&Ks[j * 16 + lr][c * 32 + lg * 8];
        s[j] = __builtin_amdgcn_mfma_f32_16x16x32_bf16(a, bb, s[j], 0, 0, 0);
      }
    }
    #pragma unroll
    for (int j = 0; j < 4; ++j)
      #pragma unroll
      for (int r = 0; r < 4; ++r)
        s[j][r] *= 0.125f;               // 1/sqrt(64)

    if (kt == qt) {
      #pragma unroll
      for (int j = 0; j < 4; ++j)
        #pragma unroll
        for (int r = 0; r < 4; ++r) {
          int row = w * 16 + lg * 4 + r;
          int col = j * 16 + lr;
          if (col > row) s[j][r] = -1e30f;
        }
    }

    // ---- online softmax
    float mx[4], al[4];
    #pragma unroll
    for (int r = 0; r < 4; ++r)
      mx[r] = fmaxf(fmaxf(s[0][r], s[1][r]), fmaxf(s[2][r], s[3][r]));
    #pragma unroll
    for (int off = 1; off <= 8; off <<= 1)
      #pragma unroll
      for (int r = 0; r < 4; ++r)
        mx[r] = fmaxf(mx[r], __shfl_xor(mx[r], off));
    #pragma unroll
    for (int r = 0; r < 4; ++r) {
      float mn = fmaxf(m[r], mx[r]);
      al[r] = __expf(m[r] - mn);
      m[r] = mn;
    }
    float rs[4] = {0.f, 0.f, 0.f, 0.f};
    #pragma unroll
    for (int j = 0; j < 4; ++j)
      #pragma unroll
      for (int r = 0; r < 4; ++r) {
        float pe = __expf(s[j][r] - m[r]);
        s[j][r] = pe;
        rs[r] += pe;
      }
    #pragma unroll
    for (int off = 1; off <= 8; off <<= 1)
      #pragma unroll
      for (int r = 0; r < 4; ++r)
        rs[r] += __shfl_xor(rs[r], off);
    #pragma unroll
    for (int r = 0; r < 4; ++r) l[r] = l[r] * al[r] + rs[r];

    #pragma unroll
    for (int j = 0; j < 4; ++j)
      #pragma unroll
      for (int r = 0; r < 4; ++r)
        oacc[j][r] *= al[r];

    // ---- P transpose via per-wave LDS
    #pragma unroll
    for (int j = 0; j < 4; ++j)
      #pragma unroll
      for (int r = 0; r < 4; ++r)
        Ps[w][lg * 4 + r][j * 16 + lr] = f2bf(s[j][r]);

    // ---- PV
    #pragma unroll
    for (int c = 0; c < 2; ++c) {
      short8 a = *(const short8*)&Ps[w][lr][c * 32 + lg * 8];
      #pragma unroll
      for (int j = 0; j < 4; ++j) {
        short8 bb = *(const short8*)&Vs[j * 16 + lr][c * 32 + lg * 8];
        oacc[j] = __builtin_amdgcn_mfma_f32_16x16x32_bf16(a, bb, oacc[j], 0, 0, 0);
      }
    }
  }

  float inv[4];
  #pragma unroll
  for (int r = 0; r < 4; ++r) inv[r] = 1.f / l[r];
  #pragma unroll
  for (int j = 0; j < 4; ++j)
    #pragma unroll
    for (int r = 0; r < 4; ++r) {
      size_t row = rowbase + qt * 64 + w * 16 + lg * 4 + r;
      o[row * DMODEL + h * 64 + j * 16 + lr] = f2bf(oacc[j][r] * inv[r]);
    }
}

// ---------------------------------------------------------------------------
// LayerNorm over last dim (128), bf16 in/out, band-indexed scale/bias.
// ---------------------------------------------------------------------------
struct LNA {
  const u16* x;
  u16* xn;
  const float* ls[7];
  const float* lb[7];
};

__global__ __launch_bounds__(256) void ln_kernel(LNA p) {
  const int tid = threadIdx.x;
  const int rr = tid >> 6, lane = tid & 63;
  const size_t row = (size_t)blockIdx.x * 4 + rr;
  u32 wv = *(const u32*)&p.x[row * DMODEL + 2 * lane];
  float a = b2f((u16)wv), b = b2f((u16)(wv >> 16));
  float s = a + b;
  #pragma unroll
  for (int off = 32; off; off >>= 1) s += __shfl_xor(s, off);
  float mean = s * (1.f / 128.f);
  float da = a - mean, db = b - mean;
  float vs = da * da + db * db;
  #pragma unroll
  for (int off = 32; off; off >>= 1) vs += __shfl_xor(vs, off);
  float rstd = rsqrtf(vs * (1.f / 128.f) + 1e-5f);
  int band = (int)(row >> 13);
  const float* ls = p.ls[band];
  const float* lb = p.lb[band];
  *(u32*)&p.xn[row * DMODEL + 2 * lane] =
      pack2(da * rstd * ls[2 * lane] + lb[2 * lane],
            db * rstd * ls[2 * lane + 1] + lb[2 * lane + 1]);
}

__global__ void bias6_kernel(const float* __restrict__ br_b, float* __restrict__ out) {
  int d = threadIdx.x;
  float s = 0.f;
  #pragma unroll
  for (int j = 0; j < 6; ++j) s += br_b[j * 128 + d];
  out[d] = s * (1.f / 6.f);
}

// fp32 -> bf16 conversion, 8 elems/thread
__global__ __launch_bounds__(256) void cvt_kernel(const float* __restrict__ in,
                                                  u16* __restrict__ out) {
  size_t i = ((size_t)blockIdx.x * 256 + threadIdx.x) * 8;
  float4 a = *(const float4*)&in[i];
  float4 b = *(const float4*)&in[i + 4];
  uint4 st = {pack2(a.x, a.y), pack2(a.z, a.w), pack2(b.x, b.y), pack2(b.z, b.w)};
  *(uint4*)&out[i] = st;
}

// ---------------------------------------------------------------------------
extern "C" void kernel_launch(void* const* d_in, const int* in_sizes, int n_in,
                              void* d_out, int out_size, void* d_ws, size_t ws_size,
                              hipStream_t stream) {
  bool dict = (in_sizes[2] != 896);
  const float* bands = (const float*)d_in[0];
  const float* Wq = (const float*)d_in[1];
  const float *Wk, *Wv, *Wo, *bq, *bk, *bv, *bo;
  if (dict) {
    Wk = (const float*)d_in[2]; Wv = (const float*)d_in[3]; Wo = (const float*)d_in[4];
    bq = (const float*)d_in[5]; bk = (const float*)d_in[6];
    bv = (const float*)d_in[7]; bo = (const float*)d_in[8];
  } else {
    bq = (const float*)d_in[2]; Wk = (const float*)d_in[3]; bk = (const float*)d_in[4];
    Wv = (const float*)d_in[5]; bv = (const float*)d_in[6];
    Wo = (const float*)d_in[7]; bo = (const float*)d_in[8];
  }
  const float* g_ls = (const float*)d_in[9];
  const float* g_lb = (const float*)d_in[10];
  const float* g_w1 = (const float*)d_in[11];
  const float* g_b1 = (const float*)d_in[12];
  const float* g_w2 = (const float*)d_in[13];
  const float* g_b2 = (const float*)d_in[14];
  const float* g_wg = (const float*)d_in[15];
  const float* g_bg = (const float*)d_in[16];
  const float* h_ls = (const float*)d_in[17];
  const float* h_lb = (const float*)d_in[18];
  const float* h_w1 = (const float*)d_in[19];
  const float* h_b1 = (const float*)d_in[20];
  const float* h_w2 = (const float*)d_in[21];
  const float* h_b2 = (const float*)d_in[22];
  const float* r_ls = (const float*)d_in[23];
  const float* r_lb = (const float*)d_in[24];
  const float* r_w1 = (const float*)d_in[25];
  const float* r_b1 = (const float*)d_in[26];
  const float* r_w2 = (const float*)d_in[27];
  const float* r_b2 = (const float*)d_in[28];
  const float* wp_w = (const float*)d_in[29];
  const float* wp_b = (const float*)d_in[30];
  const float* wg_w = (const float*)d_in[31];
  const float* wg_b = (const float*)d_in[32];
  const float* br_w = (const float*)d_in[33];
  const float* br_b = (const float*)d_in[34];
  const float* bg_w = (const float*)d_in[35];
  const float* bg_b = (const float*)d_in[36];
  float* out = (float*)d_out;

  const int hN[7] = {256, 256, 256, 384, 384, 512, 512};
  const float* lsP[7] = {g_ls, g_ls + 128, g_ls + 256, h_ls, h_ls + 128, r_ls, r_ls + 128};
  const float* lbP[7] = {g_lb, g_lb + 128, g_lb + 256, h_lb, h_lb + 128, r_lb, r_lb + 128};
  const float* w1p[7] = {g_w1, g_w1 + 32768, g_w1 + 65536,
                         h_w1, h_w1 + 49152, r_w1, r_w1 + 65536};
  const float* b1p[7] = {g_b1, g_b1 + 256, g_b1 + 512,
                         h_b1, h_b1 + 384, r_b1, r_b1 + 512};
  const float* w2p[7] = {g_w2, g_w2 + 32768, g_w2 + 65536,
                         h_w2, h_w2 + 49152, r_w2, r_w2 + 65536};
  const float* b2p[7] = {g_b2, g_b2 + 128, g_b2 + 256,
                         h_b2, h_b2 + 128, r_b2, r_b2 + 128};

  auto LP = [&](PArgs& p, int Z) {
    dim3 grid(MBAND / 64, p.N / 64, Z);
    gemm_b<<<grid, dim3(256), 0, stream>>>(p);
  };

  // ---- bf16 workspace layout (~97 MB) ----
  // hid region (8192x2304) overlays bandsH (used first) and later info/bridge.
  const size_t HIDSZ = (size_t)MBAND * 2304;
  u16* H = (u16*)d_ws;
  u16* hidh   = H;                       // HIDSZ
  u16* bandsH = hidh;                    // 7 BANDE (overlay, dead after QKV)
  u16* qh = H + HIDSZ;                   // 7 BANDE
  u16* kh = qh + 7 * BANDE;              // 7 BANDE
  u16* vh = kh + 7 * BANDE;              // 7 BANDE
  u16* oh = vh + 7 * BANDE;              // 7 BANDE
  float* bbias = (float*)(oh + 7 * BANDE);
  u16* xh = qh;                          // reuse (q dead after attn)
  u16* xnh = kh;
  u16* gateh = vh;
  u16* yh = oh;
  u16* infoh = hidh;                     // reuse (hid dead after MLP2)
  u16* bridgeh = hidh + 6 * BANDE;

  // 0. bands -> bf16
  cvt_kernel<<<dim3((unsigned)(7 * BANDE / (8 * 256))), dim3(256), 0, stream>>>(bands, bandsH);

  // 1-3. Q/K/V projections, Z=7 each
  const float* Wqkv[3] = {Wq, Wk, Wv};
  const float* bqkv[3] = {bq, bk, bv};
  u16* oqkv[3] = {qh, kh, vh};
  for (int w = 0; w < 3; ++w) {
    PArgs p{};
    p.A = bandsH; p.W = Wqkv[w]; p.bias = bqkv[w]; p.OH = oqkv[w];
    for (int z = 0; z < 7; ++z) {
      p.Aoff[z] = z * BANDE; p.Woff[z] = (size_t)z * 16384;
      p.boff[z] = (size_t)z * 128; p.Ooff[z] = z * BANDE;
    }
    p.K = 128; p.N = 128; p.op = 0;
    LP(p, 7);
  }

  // 4. attention
  attn_kernel<<<dim3(NBAND * 256), dim3(256), 0, stream>>>(qh, kh, vh, oh);

  // 5. x = bands + o @ Wo + bo   (resid fp32 input, out bf16)
  {
    PArgs p{};
    p.A = oh; p.W = Wo; p.bias = bo; p.residF = bands; p.OH = xh;
    for (int z = 0; z < 7; ++z) {
      p.Aoff[z] = z * BANDE; p.Woff[z] = (size_t)z * 16384;
      p.boff[z] = (size_t)z * 128; p.roff[z] = z * BANDE; p.Ooff[z] = z * BANDE;
    }
    p.K = 128; p.N = 128; p.op = 3;
    LP(p, 7);
  }

  // 6. LN
  {
    LNA p{};
    p.x = xh; p.xn = xnh;
    for (int n = 0; n < 7; ++n) { p.ls[n] = lsP[n]; p.lb[n] = lbP[n]; }
    ln_kernel<<<dim3(NBAND * MBAND / 4), dim3(256), 0, stream>>>(p);
  }

  // 7. geo gates, Z=3
  {
    PArgs p{};
    p.A = xh; p.W = g_wg; p.bias = g_bg; p.OH = gateh;
    for (int z = 0; z < 3; ++z) {
      p.Aoff[z] = z * BANDE; p.Woff[z] = (size_t)z * 16384;
      p.boff[z] = (size_t)z * 128; p.Ooff[z] = z * BANDE;
    }
    p.K = 128; p.N = 128; p.op = 2;
    LP(p, 3);
  }

  // 8-13. MLP per group: geo(3,256) hyb(2,384) rea(2,512)
  const int gcnt[3] = {3, 2, 2};
  const int gbase[3] = {0, 3, 5};
  for (int grp = 0; grp < 3; ++grp) {
    int cnt = gcnt[grp], base = gbase[grp], N1 = hN[base];
    size_t hstride = (size_t)MBAND * N1;
    {  // hidden = gelu(xn @ w1 + b1)
      PArgs p{};
      p.A = xnh; p.W = w1p[base]; p.bias = b1p[base]; p.OH = hidh;
      for (int z = 0; z < cnt; ++z) {
        p.Aoff[z] = (size_t)(base + z) * BANDE;
        p.Woff[z] = (size_t)(w1p[base + z] - w1p[base]);
        p.boff[z] = (size_t)(b1p[base + z] - b1p[base]);
        p.Ooff[z] = z * hstride;
      }
      p.K = 128; p.N = N1; p.op = 1;
      LP(p, cnt);
    }
    {  // y = x + [gate]*(hid @ w2 + b2)
      PArgs p{};
      p.A = hidh; p.W = w2p[base]; p.bias = b2p[base];
      p.residH = xh; p.OH = yh;
      if (grp == 0) p.extraH = gateh;
      for (int z = 0; z < cnt; ++z) {
        p.Aoff[z] = z * hstride;
        p.Woff[z] = (size_t)(w2p[base + z] - w2p[base]);
        p.boff[z] = (size_t)(b2p[base + z] - b2p[base]);
        p.roff[z] = (size_t)(base + z) * BANDE;
        p.eoff[z] = z * BANDE;
        p.Ooff[z] = (size_t)(base + z) * BANDE;
      }
      p.K = N1; p.N = 128; p.op = 5;
      LP(p, cnt);
    }
  }

  // 14. info, Z=6
  {
    PArgs p{};
    p.A = yh; p.W = wp_w; p.bias = wp_b; p.OH = infoh;
    for (int z = 0; z < 6; ++z) {
      int t = (z < 3) ? z : z + 1;
      int src = 6 - t;
      int i = (t < 3) ? t : 6 - t;
      p.Aoff[z] = (size_t)src * BANDE; p.Woff[z] = (size_t)i * 16384;
      p.boff[z] = (size_t)i * 128; p.Ooff[z] = (size_t)z * BANDE;
    }
    p.K = 128; p.N = 128; p.op = 0;
    LP(p, 6);
  }

  // 15. final gates for 6 targets (2-part K), fp32 out
  {
    PArgs p{};
    p.A = yh; p.W = wg_w; p.A2 = infoh; p.W2 = wg_w;
    p.bias = wg_b; p.residH = yh; p.extraH = infoh; p.OF = out;
    for (int z = 0; z < 6; ++z) {
      int t = (z < 3) ? z : z + 1;
      int i = (t < 3) ? t : 6 - t;
      p.Aoff[z] = (size_t)t * BANDE;  p.Woff[z] = (size_t)i * 32768;
      p.A2off[z] = (size_t)z * BANDE; p.W2off[z] = (size_t)i * 32768 + 16384;
      p.boff[z] = (size_t)i * 128;
      p.roff[z] = (size_t)t * BANDE;  p.eoff[z] = (size_t)z * BANDE;
      p.Ooff[z] = (size_t)t * BANDE;
    }
    p.K = 128; p.N = 128; p.op = 4;
    LP(p, 6);
  }

  // 16-17. bridge
  bias6_kernel<<<dim3(1), dim3(128), 0, stream>>>(br_b, bbias);
  bridge_kernel<<<dim3(MBAND / 64, 2), dim3(256), 0, stream>>>(yh, br_w, bbias, bridgeh);

  // 18. band-3 final (2-part), fp32 out
  {
    PArgs p{};
    p.A = yh; p.W = bg_w; p.A2 = bridgeh; p.W2 = bg_w;
    p.bias = bg_b; p.residH = yh; p.extraH = bridgeh; p.OF = out;
    p.Aoff[0] = 3 * BANDE; p.Woff[0] = 0;
    p.A2off[0] = 0; p.W2off[0] = 16384;
    p.boff[0] = 0; p.roff[0] = 3 * BANDE; p.eoff[0] = 0; p.Ooff[0] = 3 * BANDE;
    p.K = 128; p.N = 128; p.op = 4;
    LP(p, 1);
  }
}